// Round 4
// baseline (346.111 us; speedup 1.0000x reference)
//
#include <hip/hip_runtime.h>
#include <hip/hip_bf16.h>

#define EMB 512
#define NSTK 32
#define NPNT 64
#define BSZ 32

typedef __attribute__((ext_vector_type(8))) short bf16x8;
typedef __attribute__((ext_vector_type(4))) float f32x4;
typedef __attribute__((ext_vector_type(4))) unsigned short us4;

static __device__ __forceinline__ unsigned short bf16bits(float x) {
    __hip_bfloat16 h = __float2bfloat16(x);
    return *reinterpret_cast<unsigned short*>(&h);
}

// ---------------------------------------------------------------------------
// Kernel A: split Wk and Wg (fp32, 512x512 each) into bf16 hi + lo parts.
// ---------------------------------------------------------------------------
__global__ void cvt_weights(const float* __restrict__ wk,
                            const float* __restrict__ wg,
                            __hip_bfloat16* __restrict__ wkh,
                            __hip_bfloat16* __restrict__ wkl,
                            __hip_bfloat16* __restrict__ wgh,
                            __hip_bfloat16* __restrict__ wgl) {
    int idx = blockIdx.x * blockDim.x + threadIdx.x;   // 0..131071, 4 elems each
    const float* src;
    __hip_bfloat16 *dh, *dl;
    int k;
    if (idx < 65536) { src = wk; dh = wkh; dl = wkl; k = idx; }
    else             { src = wg; dh = wgh; dl = wgl; k = idx - 65536; }
    f32x4 v = *reinterpret_cast<const f32x4*>(src + (size_t)k * 4);
    us4 oh, ol;
#pragma unroll
    for (int e = 0; e < 4; ++e) {
        __hip_bfloat16 h = __float2bfloat16(v[e]);
        float hf = __bfloat162float(h);
        oh[e] = *reinterpret_cast<unsigned short*>(&h);
        ol[e] = bf16bits(v[e] - hf);
    }
    *reinterpret_cast<us4*>(dh + (size_t)k * 4) = oh;
    *reinterpret_cast<us4*>(dl + (size_t)k * 4) = ol;
}

// ---------------------------------------------------------------------------
// Kernel B: sp_q / sp_v — fp32 GEMM: out[m][o] = lrelu(sc[o]*dot(W[o,:],S[:,m])+bi[o])
// S[c][m] = sparse[b][c][i], m = b*32+i.  Tile 64 o x 64 m, K chunks of 32.
// ---------------------------------------------------------------------------
__global__ __launch_bounds__(256)
void qv_gemm(const float* __restrict__ sparse,
             const float* __restrict__ Wq, const float* __restrict__ sq, const float* __restrict__ bq,
             const float* __restrict__ Wv, const float* __restrict__ sv, const float* __restrict__ bv,
             float* __restrict__ outq, float* __restrict__ outv) {
    const float* W  = (blockIdx.z == 0) ? Wq : Wv;
    const float* sc = (blockIdx.z == 0) ? sq : sv;
    const float* bi = (blockIdx.z == 0) ? bq : bv;
    float* orow     = (blockIdx.z == 0) ? outq : outv;

    __shared__ float Wt[64][33];
    __shared__ float St[32][65];

    const int m0 = blockIdx.x * 64;
    const int o0 = blockIdx.y * 64;
    const int t  = threadIdx.x;
    const int ty = t >> 4, tx = t & 15;

    float acc[4][4] = {};

    for (int k0 = 0; k0 < 512; k0 += 32) {
        {   // stage W tile: 64 rows x 32 k
            int ol = t >> 2, kl = (t & 3) * 8;
            const float* p = W + (size_t)(o0 + ol) * 512 + k0 + kl;
            f32x4 v0 = *reinterpret_cast<const f32x4*>(p);
            f32x4 v1 = *reinterpret_cast<const f32x4*>(p + 4);
#pragma unroll
            for (int e = 0; e < 4; ++e) { Wt[ol][kl + e] = v0[e]; Wt[ol][kl + 4 + e] = v1[e]; }
        }
        {   // stage S tile: 32 k x 64 m
            int kl = t >> 3, ml = (t & 7) * 8;
            int mm = m0 + ml;            // ml multiple of 8 -> same b for all 8
            int bb = mm >> 5, iidx = mm & 31;
            const float* p = sparse + (size_t)bb * 16384 + (size_t)(k0 + kl) * 32 + iidx;
            f32x4 v0 = *reinterpret_cast<const f32x4*>(p);
            f32x4 v1 = *reinterpret_cast<const f32x4*>(p + 4);
#pragma unroll
            for (int e = 0; e < 4; ++e) { St[kl][ml + e] = v0[e]; St[kl][ml + 4 + e] = v1[e]; }
        }
        __syncthreads();
#pragma unroll
        for (int kk = 0; kk < 32; ++kk) {
            float av[4], bvv[4];
#pragma unroll
            for (int e = 0; e < 4; ++e) av[e]  = Wt[ty * 4 + e][kk];
#pragma unroll
            for (int e = 0; e < 4; ++e) bvv[e] = St[kk][tx * 4 + e];
#pragma unroll
            for (int a = 0; a < 4; ++a)
#pragma unroll
                for (int bb2 = 0; bb2 < 4; ++bb2) acc[a][bb2] += av[a] * bvv[bb2];
        }
        __syncthreads();
    }
#pragma unroll
    for (int ae = 0; ae < 4; ++ae) {
        int o = o0 + ty * 4 + ae;
        float s = sc[o], bb2 = bi[o];
#pragma unroll
        for (int be = 0; be < 4; ++be) {
            int mm = m0 + tx * 4 + be;
            float h = acc[ae][be] * s + bb2;
            h = (h >= 0.f) ? h : 0.2f * h;
            orow[(size_t)mm * 512 + o] = h;
        }
    }
}

// ---------------------------------------------------------------------------
// Kernel C: fused main. One WG (8 waves, 512 thr) per (b,i).
// Split-bf16 compensated GEMMs: A*B ~= Ah*Bh + Ah*Bl + Al*Bh  (error ~2^-18)
//  stage Xh/Xl[j][c] -> GEMM1 (Wk) -> d = q - lrelu(.) -> Dh/Dl over same LDS
//  -> GEMM2 (Wg) -> lrelu -> softmax over channel per j -> out = v * sum_j coef
// Output is FP32 (reference output dtype).
// ---------------------------------------------------------------------------
__global__ __launch_bounds__(512, 1)
void fused_attn(const float* __restrict__ dense,
                const __hip_bfloat16* __restrict__ wkh,
                const __hip_bfloat16* __restrict__ wkl,
                const __hip_bfloat16* __restrict__ wgh,
                const __hip_bfloat16* __restrict__ wgl,
                const float* __restrict__ wsq,
                const float* __restrict__ wsv,
                const float* __restrict__ sk, const float* __restrict__ bk,
                const float* __restrict__ sg, const float* __restrict__ bg,
                float* __restrict__ out) {
    __shared__ __align__(16) __hip_bfloat16 XH[64][520];   // 66.5 KB, reused as Dh
    __shared__ __align__(16) __hip_bfloat16 XL[64][520];   // 66.5 KB, reused as Dl
    __shared__ __align__(16) float qrow[512];
    __shared__ __align__(16) float vrow[512];
    __shared__ float wredA[8][64];
    __shared__ float wredB[8][64];

    const int m   = blockIdx.x;        // 0..1023
    const int b   = m >> 5, ii = m & 31;
    const int tid = threadIdx.x;       // 0..511
    const int w   = tid >> 6;          // wave 0..7
    const int l   = tid & 63;
    const int l15 = l & 15;
    const int lk  = l >> 4;            // 0..3

    qrow[tid] = wsq[(size_t)m * 512 + tid];
    vrow[tid] = wsv[(size_t)m * 512 + tid];

    {   // stage X split: thread handles row c = tid, all 64 j
        const float* src = dense + ((size_t)b * 512 + tid) * 2048 + (size_t)ii * 64;
#pragma unroll
        for (int j4 = 0; j4 < 16; ++j4) {
            f32x4 v = *reinterpret_cast<const f32x4*>(src + j4 * 4);
#pragma unroll
            for (int e = 0; e < 4; ++e) {
                __hip_bfloat16 h = __float2bfloat16(v[e]);
                float hf = __bfloat162float(h);
                XH[j4 * 4 + e][tid] = h;
                XL[j4 * 4 + e][tid] = __float2bfloat16(v[e] - hf);
            }
        }
    }
    __syncthreads();

    f32x4 acc[4][4];
#pragma unroll
    for (int fm = 0; fm < 4; ++fm)
#pragma unroll
        for (int fn = 0; fn < 4; ++fn) acc[fm][fn] = (f32x4){0.f, 0.f, 0.f, 0.f};

    // ---- GEMM1: dn_k[o,j] = sum_c Wk[o,c] * X[c,j]   (3-term compensated)
    for (int ks = 0; ks < 16; ++ks) {
        const int k = ks * 32 + lk * 8;
        bf16x8 ah[4], al[4], bh[4], bl[4];
#pragma unroll
        for (int fm = 0; fm < 4; ++fm) {
            size_t off = (size_t)(w * 64 + fm * 16 + l15) * 512 + k;
            ah[fm] = *reinterpret_cast<const bf16x8*>(wkh + off);
            al[fm] = *reinterpret_cast<const bf16x8*>(wkl + off);
        }
#pragma unroll
        for (int fn = 0; fn < 4; ++fn) {
            bh[fn] = *reinterpret_cast<const bf16x8*>(&XH[fn * 16 + l15][k]);
            bl[fn] = *reinterpret_cast<const bf16x8*>(&XL[fn * 16 + l15][k]);
        }
#pragma unroll
        for (int fm = 0; fm < 4; ++fm)
#pragma unroll
            for (int fn = 0; fn < 4; ++fn) {
                acc[fm][fn] = __builtin_amdgcn_mfma_f32_16x16x32_bf16(ah[fm], bh[fn], acc[fm][fn], 0, 0, 0);
                acc[fm][fn] = __builtin_amdgcn_mfma_f32_16x16x32_bf16(ah[fm], bl[fn], acc[fm][fn], 0, 0, 0);
                acc[fm][fn] = __builtin_amdgcn_mfma_f32_16x16x32_bf16(al[fm], bh[fn], acc[fm][fn], 0, 0, 0);
            }
    }
    __syncthreads();   // all waves done reading XH/XL

    // ---- epilogue1: d = q - lrelu(acc*sk+bk), split bf16, write D over X LDS
#pragma unroll
    for (int fm = 0; fm < 4; ++fm) {
        const int o0 = w * 64 + fm * 16 + lk * 4;
        f32x4 skv = *reinterpret_cast<const f32x4*>(sk + o0);
        f32x4 bkv = *reinterpret_cast<const f32x4*>(bk + o0);
        f32x4 qv4 = *reinterpret_cast<const f32x4*>(&qrow[o0]);
#pragma unroll
        for (int fn = 0; fn < 4; ++fn) {
            const int j = fn * 16 + l15;
            us4 pkh, pkl;
#pragma unroll
            for (int r = 0; r < 4; ++r) {
                float h = acc[fm][fn][r] * skv[r] + bkv[r];
                h = (h >= 0.f) ? h : 0.2f * h;
                float dv = qv4[r] - h;
                __hip_bfloat16 hb = __float2bfloat16(dv);
                float hf = __bfloat162float(hb);
                pkh[r] = *reinterpret_cast<unsigned short*>(&hb);
                pkl[r] = bf16bits(dv - hf);
            }
            *reinterpret_cast<us4*>(&XH[j][o0]) = pkh;   // 8B store, o0 % 4 == 0
            *reinterpret_cast<us4*>(&XL[j][o0]) = pkl;
        }
    }
    __syncthreads();

    // ---- GEMM2: g[oo,j] = sum_o Wg[oo,o] * d[o,j]   (3-term compensated)
#pragma unroll
    for (int fm = 0; fm < 4; ++fm)
#pragma unroll
        for (int fn = 0; fn < 4; ++fn) acc[fm][fn] = (f32x4){0.f, 0.f, 0.f, 0.f};

    for (int ks = 0; ks < 16; ++ks) {
        const int k = ks * 32 + lk * 8;
        bf16x8 ah[4], al[4], bh[4], bl[4];
#pragma unroll
        for (int fm = 0; fm < 4; ++fm) {
            size_t off = (size_t)(w * 64 + fm * 16 + l15) * 512 + k;
            ah[fm] = *reinterpret_cast<const bf16x8*>(wgh + off);
            al[fm] = *reinterpret_cast<const bf16x8*>(wgl + off);
        }
#pragma unroll
        for (int fn = 0; fn < 4; ++fn) {
            bh[fn] = *reinterpret_cast<const bf16x8*>(&XH[fn * 16 + l15][k]);
            bl[fn] = *reinterpret_cast<const bf16x8*>(&XL[fn * 16 + l15][k]);
        }
#pragma unroll
        for (int fm = 0; fm < 4; ++fm)
#pragma unroll
            for (int fn = 0; fn < 4; ++fn) {
                acc[fm][fn] = __builtin_amdgcn_mfma_f32_16x16x32_bf16(ah[fm], bh[fn], acc[fm][fn], 0, 0, 0);
                acc[fm][fn] = __builtin_amdgcn_mfma_f32_16x16x32_bf16(ah[fm], bl[fn], acc[fm][fn], 0, 0, 0);
                acc[fm][fn] = __builtin_amdgcn_mfma_f32_16x16x32_bf16(al[fm], bh[fn], acc[fm][fn], 0, 0, 0);
            }
    }

    // ---- epilogue2 in place: g = lrelu(acc*sg+bg)
#pragma unroll
    for (int fm = 0; fm < 4; ++fm) {
        const int o0 = w * 64 + fm * 16 + lk * 4;
        f32x4 sgv = *reinterpret_cast<const f32x4*>(sg + o0);
        f32x4 bgv = *reinterpret_cast<const f32x4*>(bg + o0);
#pragma unroll
        for (int fn = 0; fn < 4; ++fn)
#pragma unroll
            for (int r = 0; r < 4; ++r) {
                float h = acc[fm][fn][r] * sgv[r] + bgv[r];
                acc[fm][fn][r] = (h >= 0.f) ? h : 0.2f * h;
            }
    }

    // ---- softmax over the 512 channels, per j column
    float pm[4];
#pragma unroll
    for (int fn = 0; fn < 4; ++fn) {
        float mx = -1e30f;
#pragma unroll
        for (int fm = 0; fm < 4; ++fm)
#pragma unroll
            for (int r = 0; r < 4; ++r) mx = fmaxf(mx, acc[fm][fn][r]);
        mx = fmaxf(mx, __shfl_xor(mx, 16, 64));
        mx = fmaxf(mx, __shfl_xor(mx, 32, 64));
        pm[fn] = mx;
    }
    if (l < 16) {
#pragma unroll
        for (int fn = 0; fn < 4; ++fn) wredA[w][fn * 16 + l] = pm[fn];
    }
    __syncthreads();

    float jmax[4];
#pragma unroll
    for (int fn = 0; fn < 4; ++fn) {
        float mx = wredA[0][fn * 16 + l15];
#pragma unroll
        for (int ww = 1; ww < 8; ++ww) mx = fmaxf(mx, wredA[ww][fn * 16 + l15]);
        jmax[fn] = mx;
    }

    float ps[4] = {0.f, 0.f, 0.f, 0.f};
#pragma unroll
    for (int fm = 0; fm < 4; ++fm)
#pragma unroll
        for (int fn = 0; fn < 4; ++fn)
#pragma unroll
            for (int r = 0; r < 4; ++r) {
                float e = __expf(acc[fm][fn][r] - jmax[fn]);
                acc[fm][fn][r] = e;
                ps[fn] += e;
            }
#pragma unroll
    for (int fn = 0; fn < 4; ++fn) {
        ps[fn] += __shfl_xor(ps[fn], 16, 64);
        ps[fn] += __shfl_xor(ps[fn], 32, 64);
    }
    if (l < 16) {
#pragma unroll
        for (int fn = 0; fn < 4; ++fn) wredB[w][fn * 16 + l] = ps[fn];
    }
    __syncthreads();

    float rinv[4];
#pragma unroll
    for (int fn = 0; fn < 4; ++fn) {
        float s = 0.f;
#pragma unroll
        for (int ww = 0; ww < 8; ++ww) s += wredB[ww][fn * 16 + l15];
        rinv[fn] = 1.f / s;
    }

    // ---- out[b,oo,i] = sp_v[oo] * sum_j coef[oo,j]   (FP32 store)
#pragma unroll
    for (int fm = 0; fm < 4; ++fm) {
#pragma unroll
        for (int r = 0; r < 4; ++r) {
            float tsum = 0.f;
#pragma unroll
            for (int fn = 0; fn < 4; ++fn) tsum += acc[fm][fn][r] * rinv[fn];
            tsum += __shfl_xor(tsum, 1, 64);
            tsum += __shfl_xor(tsum, 2, 64);
            tsum += __shfl_xor(tsum, 4, 64);
            tsum += __shfl_xor(tsum, 8, 64);
            if (l15 == 0) {
                int oo = w * 64 + fm * 16 + lk * 4 + r;
                out[((size_t)b * 512 + oo) * 32 + ii] = vrow[oo] * tsum;
            }
        }
    }
}

// ---------------------------------------------------------------------------
extern "C" void kernel_launch(void* const* d_in, const int* in_sizes, int n_in,
                              void* d_out, int out_size, void* d_ws, size_t ws_size,
                              hipStream_t stream) {
    const float* sparse = (const float*)d_in[0];
    const float* dense  = (const float*)d_in[1];
    const float* Wq = (const float*)d_in[2];
    const float* sq = (const float*)d_in[3];
    const float* bq = (const float*)d_in[4];
    const float* Wk = (const float*)d_in[5];
    const float* sk = (const float*)d_in[6];
    const float* bk = (const float*)d_in[7];
    const float* Wv = (const float*)d_in[8];
    const float* sv = (const float*)d_in[9];
    const float* bv = (const float*)d_in[10];
    const float* Wg = (const float*)d_in[11];
    const float* sg = (const float*)d_in[12];
    const float* bg = (const float*)d_in[13];
    float* out = (float*)d_out;

    // workspace: [sp_q f32 2MB][sp_v f32 2MB][Wk hi/lo bf16 1MB][Wg hi/lo bf16 1MB]
    float* wsq = (float*)d_ws;
    float* wsv = wsq + 1024 * 512;
    __hip_bfloat16* wkh = (__hip_bfloat16*)(wsv + 1024 * 512);
    __hip_bfloat16* wkl = wkh + 512 * 512;
    __hip_bfloat16* wgh = wkl + 512 * 512;
    __hip_bfloat16* wgl = wgh + 512 * 512;

    cvt_weights<<<512, 256, 0, stream>>>(Wk, Wg, wkh, wkl, wgh, wgl);
    qv_gemm<<<dim3(16, 8, 2), 256, 0, stream>>>(sparse, Wq, sq, bq, Wv, sv, bv, wsq, wsv);
    fused_attn<<<1024, 512, 0, stream>>>(dense, wkh, wkl, wgh, wgl, wsq, wsv, sk, bk, sg, bg, out);
}

// Round 5
// 323.898 us; speedup vs baseline: 1.0686x; 1.0686x over previous
//
#include <hip/hip_runtime.h>
#include <hip/hip_bf16.h>

#define EMB 512
#define NSTK 32
#define NPNT 64
#define BSZ 32

typedef __attribute__((ext_vector_type(8))) short bf16x8;
typedef __attribute__((ext_vector_type(4))) float f32x4;
typedef __attribute__((ext_vector_type(4))) unsigned short us4;

static __device__ __forceinline__ unsigned short bf16bits(float x) {
    __hip_bfloat16 h = __float2bfloat16(x);
    return *reinterpret_cast<unsigned short*>(&h);
}

// ---------------------------------------------------------------------------
// Kernel A: split Wk and Wg (fp32, 512x512 each) into bf16 hi + lo parts.
// ---------------------------------------------------------------------------
__global__ void cvt_weights(const float* __restrict__ wk,
                            const float* __restrict__ wg,
                            __hip_bfloat16* __restrict__ wkh,
                            __hip_bfloat16* __restrict__ wkl,
                            __hip_bfloat16* __restrict__ wgh,
                            __hip_bfloat16* __restrict__ wgl) {
    int idx = blockIdx.x * blockDim.x + threadIdx.x;   // 0..131071, 4 elems each
    const float* src;
    __hip_bfloat16 *dh, *dl;
    int k;
    if (idx < 65536) { src = wk; dh = wkh; dl = wkl; k = idx; }
    else             { src = wg; dh = wgh; dl = wgl; k = idx - 65536; }
    f32x4 v = *reinterpret_cast<const f32x4*>(src + (size_t)k * 4);
    us4 oh, ol;
#pragma unroll
    for (int e = 0; e < 4; ++e) {
        __hip_bfloat16 h = __float2bfloat16(v[e]);
        float hf = __bfloat162float(h);
        oh[e] = *reinterpret_cast<unsigned short*>(&h);
        ol[e] = bf16bits(v[e] - hf);
    }
    *reinterpret_cast<us4*>(dh + (size_t)k * 4) = oh;
    *reinterpret_cast<us4*>(dl + (size_t)k * 4) = ol;
}

// ---------------------------------------------------------------------------
// Kernel B: sp_q / sp_v — fp32 GEMM: out[m][o] = lrelu(sc[o]*dot(W[o,:],S[:,m])+bi[o])
// ---------------------------------------------------------------------------
__global__ __launch_bounds__(256)
void qv_gemm(const float* __restrict__ sparse,
             const float* __restrict__ Wq, const float* __restrict__ sq, const float* __restrict__ bq,
             const float* __restrict__ Wv, const float* __restrict__ sv, const float* __restrict__ bv,
             float* __restrict__ outq, float* __restrict__ outv) {
    const float* W  = (blockIdx.z == 0) ? Wq : Wv;
    const float* sc = (blockIdx.z == 0) ? sq : sv;
    const float* bi = (blockIdx.z == 0) ? bq : bv;
    float* orow     = (blockIdx.z == 0) ? outq : outv;

    __shared__ float Wt[64][33];
    __shared__ float St[32][65];

    const int m0 = blockIdx.x * 64;
    const int o0 = blockIdx.y * 64;
    const int t  = threadIdx.x;
    const int ty = t >> 4, tx = t & 15;

    float acc[4][4] = {};

    for (int k0 = 0; k0 < 512; k0 += 32) {
        {
            int ol = t >> 2, kl = (t & 3) * 8;
            const float* p = W + (size_t)(o0 + ol) * 512 + k0 + kl;
            f32x4 v0 = *reinterpret_cast<const f32x4*>(p);
            f32x4 v1 = *reinterpret_cast<const f32x4*>(p + 4);
#pragma unroll
            for (int e = 0; e < 4; ++e) { Wt[ol][kl + e] = v0[e]; Wt[ol][kl + 4 + e] = v1[e]; }
        }
        {
            int kl = t >> 3, ml = (t & 7) * 8;
            int mm = m0 + ml;
            int bb = mm >> 5, iidx = mm & 31;
            const float* p = sparse + (size_t)bb * 16384 + (size_t)(k0 + kl) * 32 + iidx;
            f32x4 v0 = *reinterpret_cast<const f32x4*>(p);
            f32x4 v1 = *reinterpret_cast<const f32x4*>(p + 4);
#pragma unroll
            for (int e = 0; e < 4; ++e) { St[kl][ml + e] = v0[e]; St[kl][ml + 4 + e] = v1[e]; }
        }
        __syncthreads();
#pragma unroll
        for (int kk = 0; kk < 32; ++kk) {
            float av[4], bvv[4];
#pragma unroll
            for (int e = 0; e < 4; ++e) av[e]  = Wt[ty * 4 + e][kk];
#pragma unroll
            for (int e = 0; e < 4; ++e) bvv[e] = St[kk][tx * 4 + e];
#pragma unroll
            for (int a = 0; a < 4; ++a)
#pragma unroll
                for (int bb2 = 0; bb2 < 4; ++bb2) acc[a][bb2] += av[a] * bvv[bb2];
        }
        __syncthreads();
    }
#pragma unroll
    for (int ae = 0; ae < 4; ++ae) {
        int o = o0 + ty * 4 + ae;
        float s = sc[o], bb2 = bi[o];
#pragma unroll
        for (int be = 0; be < 4; ++be) {
            int mm = m0 + tx * 4 + be;
            float h = acc[ae][be] * s + bb2;
            h = (h >= 0.f) ? h : 0.2f * h;
            orow[(size_t)mm * 512 + o] = h;
        }
    }
}

// ---------------------------------------------------------------------------
// Kernel C: fused main. One WG (16 waves, 1024 thr) per (b,i).
// Wave w owns o-slice [w*32, w*32+32)  (fm in {0,1}).
// Split-bf16 compensated GEMMs: A*B ~= Ah*Bh + Ah*Bl + Al*Bh.
// ---------------------------------------------------------------------------
__global__ __launch_bounds__(1024, 4)
void fused_attn(const float* __restrict__ dense,
                const __hip_bfloat16* __restrict__ wkh,
                const __hip_bfloat16* __restrict__ wkl,
                const __hip_bfloat16* __restrict__ wgh,
                const __hip_bfloat16* __restrict__ wgl,
                const float* __restrict__ wsq,
                const float* __restrict__ wsv,
                const float* __restrict__ sk, const float* __restrict__ bk,
                const float* __restrict__ sg, const float* __restrict__ bg,
                float* __restrict__ out) {
    __shared__ __align__(16) __hip_bfloat16 XH[64][520];   // 66.5 KB, reused as Dh
    __shared__ __align__(16) __hip_bfloat16 XL[64][520];   // 66.5 KB, reused as Dl
    __shared__ __align__(16) float qrow[512];
    __shared__ __align__(16) float vrow[512];
    __shared__ float wredA[16][64];
    __shared__ float wredB[16][64];

    const int m   = blockIdx.x;        // 0..1023
    const int b   = m >> 5, ii = m & 31;
    const int tid = threadIdx.x;       // 0..1023
    const int w   = tid >> 6;          // wave 0..15
    const int l   = tid & 63;
    const int l15 = l & 15;
    const int lk  = l >> 4;            // 0..3

    if (tid < 512) qrow[tid] = wsq[(size_t)m * 512 + tid];
    else           vrow[tid - 512] = wsv[(size_t)m * 512 + (tid - 512)];

    {   // stage X split: thread t handles row c = t>>1, j-half (t&1)*32
        const int c  = tid >> 1;
        const int jh = (tid & 1) * 32;
        const float* src = dense + ((size_t)b * 512 + c) * 2048 + (size_t)ii * 64 + jh;
#pragma unroll
        for (int j4 = 0; j4 < 8; ++j4) {
            f32x4 v = *reinterpret_cast<const f32x4*>(src + j4 * 4);
#pragma unroll
            for (int e = 0; e < 4; ++e) {
                __hip_bfloat16 h = __float2bfloat16(v[e]);
                float hf = __bfloat162float(h);
                XH[jh + j4 * 4 + e][c] = h;
                XL[jh + j4 * 4 + e][c] = __float2bfloat16(v[e] - hf);
            }
        }
    }
    __syncthreads();

    f32x4 acc[2][4];
#pragma unroll
    for (int fm = 0; fm < 2; ++fm)
#pragma unroll
        for (int fn = 0; fn < 4; ++fn) acc[fm][fn] = (f32x4){0.f, 0.f, 0.f, 0.f};

    // ---- GEMM1: dn_k[o,j] = sum_c Wk[o,c] * X[c,j]   (3-term compensated)
    for (int ks = 0; ks < 16; ++ks) {
        const int k = ks * 32 + lk * 8;
        bf16x8 bh[4], bl[4];
#pragma unroll
        for (int fn = 0; fn < 4; ++fn) {
            bh[fn] = *reinterpret_cast<const bf16x8*>(&XH[fn * 16 + l15][k]);
            bl[fn] = *reinterpret_cast<const bf16x8*>(&XL[fn * 16 + l15][k]);
        }
#pragma unroll
        for (int fm = 0; fm < 2; ++fm) {
            size_t off = (size_t)(w * 32 + fm * 16 + l15) * 512 + k;
            bf16x8 ah = *reinterpret_cast<const bf16x8*>(wkh + off);
            bf16x8 al = *reinterpret_cast<const bf16x8*>(wkl + off);
#pragma unroll
            for (int fn = 0; fn < 4; ++fn) {
                acc[fm][fn] = __builtin_amdgcn_mfma_f32_16x16x32_bf16(ah, bh[fn], acc[fm][fn], 0, 0, 0);
                acc[fm][fn] = __builtin_amdgcn_mfma_f32_16x16x32_bf16(ah, bl[fn], acc[fm][fn], 0, 0, 0);
                acc[fm][fn] = __builtin_amdgcn_mfma_f32_16x16x32_bf16(al, bh[fn], acc[fm][fn], 0, 0, 0);
            }
        }
    }
    __syncthreads();   // all waves done reading XH/XL

    // ---- epilogue1: d = q - lrelu(acc*sk+bk), split bf16, write D over X LDS
#pragma unroll
    for (int fm = 0; fm < 2; ++fm) {
        const int o0 = w * 32 + fm * 16 + lk * 4;
        f32x4 skv = *reinterpret_cast<const f32x4*>(sk + o0);
        f32x4 bkv = *reinterpret_cast<const f32x4*>(bk + o0);
        f32x4 qv4 = *reinterpret_cast<const f32x4*>(&qrow[o0]);
#pragma unroll
        for (int fn = 0; fn < 4; ++fn) {
            const int j = fn * 16 + l15;
            us4 pkh, pkl;
#pragma unroll
            for (int r = 0; r < 4; ++r) {
                float h = acc[fm][fn][r] * skv[r] + bkv[r];
                h = (h >= 0.f) ? h : 0.2f * h;
                float dv = qv4[r] - h;
                __hip_bfloat16 hb = __float2bfloat16(dv);
                float hf = __bfloat162float(hb);
                pkh[r] = *reinterpret_cast<unsigned short*>(&hb);
                pkl[r] = bf16bits(dv - hf);
            }
            *reinterpret_cast<us4*>(&XH[j][o0]) = pkh;   // 8B store, o0 % 4 == 0
            *reinterpret_cast<us4*>(&XL[j][o0]) = pkl;
        }
    }
    __syncthreads();

    // ---- GEMM2: g[oo,j] = sum_o Wg[oo,o] * d[o,j]   (3-term compensated)
#pragma unroll
    for (int fm = 0; fm < 2; ++fm)
#pragma unroll
        for (int fn = 0; fn < 4; ++fn) acc[fm][fn] = (f32x4){0.f, 0.f, 0.f, 0.f};

    for (int ks = 0; ks < 16; ++ks) {
        const int k = ks * 32 + lk * 8;
        bf16x8 bh[4], bl[4];
#pragma unroll
        for (int fn = 0; fn < 4; ++fn) {
            bh[fn] = *reinterpret_cast<const bf16x8*>(&XH[fn * 16 + l15][k]);
            bl[fn] = *reinterpret_cast<const bf16x8*>(&XL[fn * 16 + l15][k]);
        }
#pragma unroll
        for (int fm = 0; fm < 2; ++fm) {
            size_t off = (size_t)(w * 32 + fm * 16 + l15) * 512 + k;
            bf16x8 ah = *reinterpret_cast<const bf16x8*>(wgh + off);
            bf16x8 al = *reinterpret_cast<const bf16x8*>(wgl + off);
#pragma unroll
            for (int fn = 0; fn < 4; ++fn) {
                acc[fm][fn] = __builtin_amdgcn_mfma_f32_16x16x32_bf16(ah, bh[fn], acc[fm][fn], 0, 0, 0);
                acc[fm][fn] = __builtin_amdgcn_mfma_f32_16x16x32_bf16(ah, bl[fn], acc[fm][fn], 0, 0, 0);
                acc[fm][fn] = __builtin_amdgcn_mfma_f32_16x16x32_bf16(al, bh[fn], acc[fm][fn], 0, 0, 0);
            }
        }
    }

    // ---- epilogue2 in place: g = lrelu(acc*sg+bg)
#pragma unroll
    for (int fm = 0; fm < 2; ++fm) {
        const int o0 = w * 32 + fm * 16 + lk * 4;
        f32x4 sgv = *reinterpret_cast<const f32x4*>(sg + o0);
        f32x4 bgv = *reinterpret_cast<const f32x4*>(bg + o0);
#pragma unroll
        for (int fn = 0; fn < 4; ++fn)
#pragma unroll
            for (int r = 0; r < 4; ++r) {
                float h = acc[fm][fn][r] * sgv[r] + bgv[r];
                acc[fm][fn][r] = (h >= 0.f) ? h : 0.2f * h;
            }
    }

    // ---- softmax over the 512 channels, per j column
    float pm[4];
#pragma unroll
    for (int fn = 0; fn < 4; ++fn) {
        float mx = -1e30f;
#pragma unroll
        for (int fm = 0; fm < 2; ++fm)
#pragma unroll
            for (int r = 0; r < 4; ++r) mx = fmaxf(mx, acc[fm][fn][r]);
        mx = fmaxf(mx, __shfl_xor(mx, 16, 64));
        mx = fmaxf(mx, __shfl_xor(mx, 32, 64));
        pm[fn] = mx;
    }
    if (l < 16) {
#pragma unroll
        for (int fn = 0; fn < 4; ++fn) wredA[w][fn * 16 + l] = pm[fn];
    }
    __syncthreads();

    float jmax[4];
#pragma unroll
    for (int fn = 0; fn < 4; ++fn) {
        float mx = wredA[0][fn * 16 + l15];
#pragma unroll
        for (int ww = 1; ww < 16; ++ww) mx = fmaxf(mx, wredA[ww][fn * 16 + l15]);
        jmax[fn] = mx;
    }

    float ps[4] = {0.f, 0.f, 0.f, 0.f};
#pragma unroll
    for (int fm = 0; fm < 2; ++fm)
#pragma unroll
        for (int fn = 0; fn < 4; ++fn)
#pragma unroll
            for (int r = 0; r < 4; ++r) {
                float e = __expf(acc[fm][fn][r] - jmax[fn]);
                acc[fm][fn][r] = e;
                ps[fn] += e;
            }
#pragma unroll
    for (int fn = 0; fn < 4; ++fn) {
        ps[fn] += __shfl_xor(ps[fn], 16, 64);
        ps[fn] += __shfl_xor(ps[fn], 32, 64);
    }
    if (l < 16) {
#pragma unroll
        for (int fn = 0; fn < 4; ++fn) wredB[w][fn * 16 + l] = ps[fn];
    }
    __syncthreads();

    float rinv[4];
#pragma unroll
    for (int fn = 0; fn < 4; ++fn) {
        float s = 0.f;
#pragma unroll
        for (int ww = 0; ww < 16; ++ww) s += wredB[ww][fn * 16 + l15];
        rinv[fn] = 1.f / s;
    }

    // ---- out[b,oo,i] = sp_v[oo] * sum_j coef[oo,j]   (FP32 store)
#pragma unroll
    for (int fm = 0; fm < 2; ++fm) {
#pragma unroll
        for (int r = 0; r < 4; ++r) {
            float tsum = 0.f;
#pragma unroll
            for (int fn = 0; fn < 4; ++fn) tsum += acc[fm][fn][r] * rinv[fn];
            tsum += __shfl_xor(tsum, 1, 64);
            tsum += __shfl_xor(tsum, 2, 64);
            tsum += __shfl_xor(tsum, 4, 64);
            tsum += __shfl_xor(tsum, 8, 64);
            if (l15 == 0) {
                int oo = w * 32 + fm * 16 + lk * 4 + r;
                out[((size_t)b * 512 + oo) * 32 + ii] = vrow[oo] * tsum;
            }
        }
    }
}

// ---------------------------------------------------------------------------
extern "C" void kernel_launch(void* const* d_in, const int* in_sizes, int n_in,
                              void* d_out, int out_size, void* d_ws, size_t ws_size,
                              hipStream_t stream) {
    const float* sparse = (const float*)d_in[0];
    const float* dense  = (const float*)d_in[1];
    const float* Wq = (const float*)d_in[2];
    const float* sq = (const float*)d_in[3];
    const float* bq = (const float*)d_in[4];
    const float* Wk = (const float*)d_in[5];
    const float* sk = (const float*)d_in[6];
    const float* bk = (const float*)d_in[7];
    const float* Wv = (const float*)d_in[8];
    const float* sv = (const float*)d_in[9];
    const float* bv = (const float*)d_in[10];
    const float* Wg = (const float*)d_in[11];
    const float* sg = (const float*)d_in[12];
    const float* bg = (const float*)d_in[13];
    float* out = (float*)d_out;

    // workspace: [sp_q f32 2MB][sp_v f32 2MB][Wk hi/lo bf16 1MB][Wg hi/lo bf16 1MB]
    float* wsq = (float*)d_ws;
    float* wsv = wsq + 1024 * 512;
    __hip_bfloat16* wkh = (__hip_bfloat16*)(wsv + 1024 * 512);
    __hip_bfloat16* wkl = wkh + 512 * 512;
    __hip_bfloat16* wgh = wkl + 512 * 512;
    __hip_bfloat16* wgl = wgh + 512 * 512;

    cvt_weights<<<512, 256, 0, stream>>>(Wk, Wg, wkh, wkl, wgh, wgl);
    qv_gemm<<<dim3(16, 8, 2), 256, 0, stream>>>(sparse, Wq, sq, bq, Wv, sv, bv, wsq, wsv);
    fused_attn<<<1024, 1024, 0, stream>>>(dense, wkh, wkl, wgh, wgl, wsq, wsv, sk, bk, sg, bg, out);
}

// Round 6
// 296.936 us; speedup vs baseline: 1.1656x; 1.0908x over previous
//
#include <hip/hip_runtime.h>
#include <hip/hip_bf16.h>

#define EMB 512
#define NSTK 32
#define NPNT 64
#define BSZ 32

typedef __attribute__((ext_vector_type(8))) short bf16x8;
typedef __attribute__((ext_vector_type(4))) float f32x4;
typedef __attribute__((ext_vector_type(4))) unsigned short us4;
typedef __attribute__((ext_vector_type(8))) unsigned short us8;

static __device__ __forceinline__ unsigned short bf16bits(float x) {
    __hip_bfloat16 h = __float2bfloat16(x);
    return *reinterpret_cast<unsigned short*>(&h);
}

// ---------------------------------------------------------------------------
// Kernel A: split Wk and Wg (fp32, 512x512 each) into bf16 hi + lo parts.
// ---------------------------------------------------------------------------
__global__ void cvt_weights(const float* __restrict__ wk,
                            const float* __restrict__ wg,
                            __hip_bfloat16* __restrict__ wkh,
                            __hip_bfloat16* __restrict__ wkl,
                            __hip_bfloat16* __restrict__ wgh,
                            __hip_bfloat16* __restrict__ wgl) {
    int idx = blockIdx.x * blockDim.x + threadIdx.x;   // 0..131071, 4 elems each
    const float* src;
    __hip_bfloat16 *dh, *dl;
    int k;
    if (idx < 65536) { src = wk; dh = wkh; dl = wkl; k = idx; }
    else             { src = wg; dh = wgh; dl = wgl; k = idx - 65536; }
    f32x4 v = *reinterpret_cast<const f32x4*>(src + (size_t)k * 4);
    us4 oh, ol;
#pragma unroll
    for (int e = 0; e < 4; ++e) {
        __hip_bfloat16 h = __float2bfloat16(v[e]);
        float hf = __bfloat162float(h);
        oh[e] = *reinterpret_cast<unsigned short*>(&h);
        ol[e] = bf16bits(v[e] - hf);
    }
    *reinterpret_cast<us4*>(dh + (size_t)k * 4) = oh;
    *reinterpret_cast<us4*>(dl + (size_t)k * 4) = ol;
}

// ---------------------------------------------------------------------------
// Kernel B: sp_q / sp_v — fp32 GEMM: out[m][o] = lrelu(sc[o]*dot(W[o,:],S[:,m])+bi[o])
// ---------------------------------------------------------------------------
__global__ __launch_bounds__(256)
void qv_gemm(const float* __restrict__ sparse,
             const float* __restrict__ Wq, const float* __restrict__ sq, const float* __restrict__ bq,
             const float* __restrict__ Wv, const float* __restrict__ sv, const float* __restrict__ bv,
             float* __restrict__ outq, float* __restrict__ outv) {
    const float* W  = (blockIdx.z == 0) ? Wq : Wv;
    const float* sc = (blockIdx.z == 0) ? sq : sv;
    const float* bi = (blockIdx.z == 0) ? bq : bv;
    float* orow     = (blockIdx.z == 0) ? outq : outv;

    __shared__ float Wt[64][33];
    __shared__ float St[32][65];

    const int m0 = blockIdx.x * 64;
    const int o0 = blockIdx.y * 64;
    const int t  = threadIdx.x;
    const int ty = t >> 4, tx = t & 15;

    float acc[4][4] = {};

    for (int k0 = 0; k0 < 512; k0 += 32) {
        {
            int ol = t >> 2, kl = (t & 3) * 8;
            const float* p = W + (size_t)(o0 + ol) * 512 + k0 + kl;
            f32x4 v0 = *reinterpret_cast<const f32x4*>(p);
            f32x4 v1 = *reinterpret_cast<const f32x4*>(p + 4);
#pragma unroll
            for (int e = 0; e < 4; ++e) { Wt[ol][kl + e] = v0[e]; Wt[ol][kl + 4 + e] = v1[e]; }
        }
        {
            int kl = t >> 3, ml = (t & 7) * 8;
            int mm = m0 + ml;
            int bb = mm >> 5, iidx = mm & 31;
            const float* p = sparse + (size_t)bb * 16384 + (size_t)(k0 + kl) * 32 + iidx;
            f32x4 v0 = *reinterpret_cast<const f32x4*>(p);
            f32x4 v1 = *reinterpret_cast<const f32x4*>(p + 4);
#pragma unroll
            for (int e = 0; e < 4; ++e) { St[kl][ml + e] = v0[e]; St[kl][ml + 4 + e] = v1[e]; }
        }
        __syncthreads();
#pragma unroll
        for (int kk = 0; kk < 32; ++kk) {
            float av[4], bvv[4];
#pragma unroll
            for (int e = 0; e < 4; ++e) av[e]  = Wt[ty * 4 + e][kk];
#pragma unroll
            for (int e = 0; e < 4; ++e) bvv[e] = St[kk][tx * 4 + e];
#pragma unroll
            for (int a = 0; a < 4; ++a)
#pragma unroll
                for (int bb2 = 0; bb2 < 4; ++bb2) acc[a][bb2] += av[a] * bvv[bb2];
        }
        __syncthreads();
    }
#pragma unroll
    for (int ae = 0; ae < 4; ++ae) {
        int o = o0 + ty * 4 + ae;
        float s = sc[o], bb2 = bi[o];
#pragma unroll
        for (int be = 0; be < 4; ++be) {
            int mm = m0 + tx * 4 + be;
            float h = acc[ae][be] * s + bb2;
            h = (h >= 0.f) ? h : 0.2f * h;
            orow[(size_t)mm * 512 + o] = h;
        }
    }
}

// ---------------------------------------------------------------------------
// Kernel C: fused main. One WG (8 waves, 512 thr) per (b,i), 2 blocks/CU.
// 2-term compensated GEMMs: A*B ~= Ah*Bh + Al*Bh  (weights ~fp32, acts bf16).
// Wave w owns o-slice [w*64, w*64+64)  (fm in 0..3).
// ---------------------------------------------------------------------------
__global__ __launch_bounds__(512, 4)
void fused_attn(const float* __restrict__ dense,
                const __hip_bfloat16* __restrict__ wkh,
                const __hip_bfloat16* __restrict__ wkl,
                const __hip_bfloat16* __restrict__ wgh,
                const __hip_bfloat16* __restrict__ wgl,
                const float* __restrict__ wsq,
                const float* __restrict__ wsv,
                const float* __restrict__ sk, const float* __restrict__ bk,
                const float* __restrict__ sg, const float* __restrict__ bg,
                float* __restrict__ out) {
    __shared__ __align__(16) __hip_bfloat16 XH[64][520];   // 66.5 KB, X -> Dh
    __shared__ __align__(16) float qrow[512];
    __shared__ __align__(16) float vrow[512];
    __shared__ float wredA[8][64];
    __shared__ float wredB[8][64];

    const int m   = blockIdx.x;        // 0..1023
    const int b   = m >> 5, ii = m & 31;
    const int tid = threadIdx.x;       // 0..511
    const int w   = tid >> 6;          // wave 0..7
    const int l   = tid & 63;
    const int l15 = l & 15;
    const int lk  = l >> 4;            // 0..3

    qrow[tid] = wsq[(size_t)m * 512 + tid];
    vrow[tid] = wsv[(size_t)m * 512 + tid];

    {   // stage X: thread owns j-row l, c-block [w*64, +64); b128 LDS writes
        const float* src = dense + (size_t)b * 512 * 2048 + (size_t)ii * 64 + l;
#pragma unroll
        for (int e8 = 0; e8 < 8; ++e8) {
            const int c0 = w * 64 + e8 * 8;
            us8 pk;
#pragma unroll
            for (int e = 0; e < 8; ++e)
                pk[e] = bf16bits(src[(size_t)(c0 + e) * 2048]);
            *reinterpret_cast<us8*>(&XH[l][c0]) = pk;
        }
    }
    __syncthreads();

    f32x4 acc[4][4];
#pragma unroll
    for (int fm = 0; fm < 4; ++fm)
#pragma unroll
        for (int fn = 0; fn < 4; ++fn) acc[fm][fn] = (f32x4){0.f, 0.f, 0.f, 0.f};

    // ---- GEMM1: dn_k[o,j] = sum_c Wk[o,c] * X[c,j]   (Ah+Al compensated)
    for (int ks = 0; ks < 16; ++ks) {
        const int k = ks * 32 + lk * 8;
        bf16x8 bh[4];
#pragma unroll
        for (int fn = 0; fn < 4; ++fn)
            bh[fn] = *reinterpret_cast<const bf16x8*>(&XH[fn * 16 + l15][k]);
        const size_t abase = (size_t)(w * 64 + l15) * 512 + k;
        bf16x8 ah = *reinterpret_cast<const bf16x8*>(wkh + abase);
        bf16x8 al = *reinterpret_cast<const bf16x8*>(wkl + abase);
#pragma unroll
        for (int fm = 0; fm < 4; ++fm) {
            bf16x8 ahn, aln;
            if (fm < 3) {   // prefetch next fm's A fragments
                ahn = *reinterpret_cast<const bf16x8*>(wkh + abase + (size_t)(fm + 1) * 16 * 512);
                aln = *reinterpret_cast<const bf16x8*>(wkl + abase + (size_t)(fm + 1) * 16 * 512);
            }
#pragma unroll
            for (int fn = 0; fn < 4; ++fn) {
                acc[fm][fn] = __builtin_amdgcn_mfma_f32_16x16x32_bf16(ah, bh[fn], acc[fm][fn], 0, 0, 0);
                acc[fm][fn] = __builtin_amdgcn_mfma_f32_16x16x32_bf16(al, bh[fn], acc[fm][fn], 0, 0, 0);
            }
            ah = ahn; al = aln;
        }
    }
    __syncthreads();   // all waves done reading XH

    // ---- epilogue1: d = q - lrelu(acc*sk+bk), bf16, write Dh over XH
#pragma unroll
    for (int fm = 0; fm < 4; ++fm) {
        const int o0 = w * 64 + fm * 16 + lk * 4;
        f32x4 skv = *reinterpret_cast<const f32x4*>(sk + o0);
        f32x4 bkv = *reinterpret_cast<const f32x4*>(bk + o0);
        f32x4 qv4 = *reinterpret_cast<const f32x4*>(&qrow[o0]);
#pragma unroll
        for (int fn = 0; fn < 4; ++fn) {
            const int j = fn * 16 + l15;
            us4 pkh;
#pragma unroll
            for (int r = 0; r < 4; ++r) {
                float h = acc[fm][fn][r] * skv[r] + bkv[r];
                h = (h >= 0.f) ? h : 0.2f * h;
                pkh[r] = bf16bits(qv4[r] - h);
            }
            *reinterpret_cast<us4*>(&XH[j][o0]) = pkh;   // 8B store, o0 % 4 == 0
        }
    }
    __syncthreads();

    // ---- GEMM2: g[oo,j] = sum_o Wg[oo,o] * d[o,j]   (Ah+Al compensated)
#pragma unroll
    for (int fm = 0; fm < 4; ++fm)
#pragma unroll
        for (int fn = 0; fn < 4; ++fn) acc[fm][fn] = (f32x4){0.f, 0.f, 0.f, 0.f};

    for (int ks = 0; ks < 16; ++ks) {
        const int k = ks * 32 + lk * 8;
        bf16x8 bh[4];
#pragma unroll
        for (int fn = 0; fn < 4; ++fn)
            bh[fn] = *reinterpret_cast<const bf16x8*>(&XH[fn * 16 + l15][k]);
        const size_t abase = (size_t)(w * 64 + l15) * 512 + k;
        bf16x8 ah = *reinterpret_cast<const bf16x8*>(wgh + abase);
        bf16x8 al = *reinterpret_cast<const bf16x8*>(wgl + abase);
#pragma unroll
        for (int fm = 0; fm < 4; ++fm) {
            bf16x8 ahn, aln;
            if (fm < 3) {
                ahn = *reinterpret_cast<const bf16x8*>(wgh + abase + (size_t)(fm + 1) * 16 * 512);
                aln = *reinterpret_cast<const bf16x8*>(wgl + abase + (size_t)(fm + 1) * 16 * 512);
            }
#pragma unroll
            for (int fn = 0; fn < 4; ++fn) {
                acc[fm][fn] = __builtin_amdgcn_mfma_f32_16x16x32_bf16(ah, bh[fn], acc[fm][fn], 0, 0, 0);
                acc[fm][fn] = __builtin_amdgcn_mfma_f32_16x16x32_bf16(al, bh[fn], acc[fm][fn], 0, 0, 0);
            }
            ah = ahn; al = aln;
        }
    }

    // ---- epilogue2 in place: g = lrelu(acc*sg+bg)
#pragma unroll
    for (int fm = 0; fm < 4; ++fm) {
        const int o0 = w * 64 + fm * 16 + lk * 4;
        f32x4 sgv = *reinterpret_cast<const f32x4*>(sg + o0);
        f32x4 bgv = *reinterpret_cast<const f32x4*>(bg + o0);
#pragma unroll
        for (int fn = 0; fn < 4; ++fn)
#pragma unroll
            for (int r = 0; r < 4; ++r) {
                float h = acc[fm][fn][r] * sgv[r] + bgv[r];
                acc[fm][fn][r] = (h >= 0.f) ? h : 0.2f * h;
            }
    }

    // ---- softmax over the 512 channels, per j column
    float pm[4];
#pragma unroll
    for (int fn = 0; fn < 4; ++fn) {
        float mx = -1e30f;
#pragma unroll
        for (int fm = 0; fm < 4; ++fm)
#pragma unroll
            for (int r = 0; r < 4; ++r) mx = fmaxf(mx, acc[fm][fn][r]);
        mx = fmaxf(mx, __shfl_xor(mx, 16, 64));
        mx = fmaxf(mx, __shfl_xor(mx, 32, 64));
        pm[fn] = mx;
    }
    if (l < 16) {
#pragma unroll
        for (int fn = 0; fn < 4; ++fn) wredA[w][fn * 16 + l] = pm[fn];
    }
    __syncthreads();

    float jmax[4];
#pragma unroll
    for (int fn = 0; fn < 4; ++fn) {
        float mx = wredA[0][fn * 16 + l15];
#pragma unroll
        for (int ww = 1; ww < 8; ++ww) mx = fmaxf(mx, wredA[ww][fn * 16 + l15]);
        jmax[fn] = mx;
    }

    float ps[4] = {0.f, 0.f, 0.f, 0.f};
#pragma unroll
    for (int fm = 0; fm < 4; ++fm)
#pragma unroll
        for (int fn = 0; fn < 4; ++fn)
#pragma unroll
            for (int r = 0; r < 4; ++r) {
                float e = __expf(acc[fm][fn][r] - jmax[fn]);
                acc[fm][fn][r] = e;
                ps[fn] += e;
            }
#pragma unroll
    for (int fn = 0; fn < 4; ++fn) {
        ps[fn] += __shfl_xor(ps[fn], 16, 64);
        ps[fn] += __shfl_xor(ps[fn], 32, 64);
    }
    if (l < 16) {
#pragma unroll
        for (int fn = 0; fn < 4; ++fn) wredB[w][fn * 16 + l] = ps[fn];
    }
    __syncthreads();

    float rinv[4];
#pragma unroll
    for (int fn = 0; fn < 4; ++fn) {
        float s = 0.f;
#pragma unroll
        for (int ww = 0; ww < 8; ++ww) s += wredB[ww][fn * 16 + l15];
        rinv[fn] = 1.f / s;
    }

    // ---- out[b,oo,i] = sp_v[oo] * sum_j coef[oo,j]   (FP32 store)
#pragma unroll
    for (int fm = 0; fm < 4; ++fm) {
#pragma unroll
        for (int r = 0; r < 4; ++r) {
            float tsum = 0.f;
#pragma unroll
            for (int fn = 0; fn < 4; ++fn) tsum += acc[fm][fn][r] * rinv[fn];
            tsum += __shfl_xor(tsum, 1, 64);
            tsum += __shfl_xor(tsum, 2, 64);
            tsum += __shfl_xor(tsum, 4, 64);
            tsum += __shfl_xor(tsum, 8, 64);
            if (l15 == 0) {
                int oo = w * 64 + fm * 16 + lk * 4 + r;
                out[((size_t)b * 512 + oo) * 32 + ii] = vrow[oo] * tsum;
            }
        }
    }
}

// ---------------------------------------------------------------------------
extern "C" void kernel_launch(void* const* d_in, const int* in_sizes, int n_in,
                              void* d_out, int out_size, void* d_ws, size_t ws_size,
                              hipStream_t stream) {
    const float* sparse = (const float*)d_in[0];
    const float* dense  = (const float*)d_in[1];
    const float* Wq = (const float*)d_in[2];
    const float* sq = (const float*)d_in[3];
    const float* bq = (const float*)d_in[4];
    const float* Wk = (const float*)d_in[5];
    const float* sk = (const float*)d_in[6];
    const float* bk = (const float*)d_in[7];
    const float* Wv = (const float*)d_in[8];
    const float* sv = (const float*)d_in[9];
    const float* bv = (const float*)d_in[10];
    const float* Wg = (const float*)d_in[11];
    const float* sg = (const float*)d_in[12];
    const float* bg = (const float*)d_in[13];
    float* out = (float*)d_out;

    // workspace: [sp_q f32 2MB][sp_v f32 2MB][Wk hi/lo bf16 1MB][Wg hi/lo bf16 1MB]
    float* wsq = (float*)d_ws;
    float* wsv = wsq + 1024 * 512;
    __hip_bfloat16* wkh = (__hip_bfloat16*)(wsv + 1024 * 512);
    __hip_bfloat16* wkl = wkh + 512 * 512;
    __hip_bfloat16* wgh = wkl + 512 * 512;
    __hip_bfloat16* wgl = wgh + 512 * 512;

    cvt_weights<<<512, 256, 0, stream>>>(Wk, Wg, wkh, wkl, wgh, wgl);
    qv_gemm<<<dim3(16, 8, 2), 256, 0, stream>>>(sparse, Wq, sq, bq, Wv, sv, bv, wsq, wsv);
    fused_attn<<<1024, 512, 0, stream>>>(dense, wkh, wkl, wgh, wgl, wsq, wsv, sk, bk, sg, bg, out);
}